// Round 1
// baseline (481.648 us; speedup 1.0000x reference)
//
#include <hip/hip_runtime.h>

#define BETA   0.5f
#define INVB   2.0f      // 1/beta
#define TOL    0.1f
#define EPS    1e-8f
#define NITER  50

// ---------------------------------------------------------------------------
// Implicit-T formulation:
//   T_k[n,m]   = exp(LD_k[n] + LS_k[m] - (k/beta)*C[n,m])        (masked via -inf)
//   Q_k        = A .* T_k = exp(LD_k + LS_k - ((k+1)/beta)*C)
//   b_k[n]     = sum_m Q_k[n,m]*sigma_k[m]
//              = sum_m exp(LD_k[n] + LS_k[m] + lsig_k[m] - ((k+1)/beta)*C)
//   delta      = mu / masked(b);  LD_{k+1} = LD_k + log(delta)
//   a[m]       = sum_n exp(LD_{k+1}[n] + LS_k[m] - ((k+1)/beta)*C)
//   sigma'     = mu / masked(a);  LS_{k+1} = LS_k + log(sigma')
//   err_k      = max_n sum_m |T_{k+1} - T_k|
// Invalid rows/cols carry LD/LS = -inf so exp() masks them to 0 automatically.
// ---------------------------------------------------------------------------

__device__ inline float wave_sum(float v) {
    for (int o = 32; o > 0; o >>= 1) v += __shfl_down(v, o, 64);
    return v;   // lane 0 holds the sum
}

__device__ inline bool mask_read(const void* mraw, int mode, int idx) {
    if (mode == 1) return ((const unsigned char*)mraw)[idx] != 0;
    if (mode == 2) return ((const float*)mraw)[idx] != 0.0f;
    return ((const int*)mraw)[idx] != 0;
}

// derived "done" state: any past iteration's err below tol (frozen slots stay 0,
// which is < tol -> monotone sticky, matching the reference's done flag)
__device__ inline bool is_done(const float* err, int it) {
    for (int j = 0; j < it; ++j)
        if (err[j] < TOL) return true;
    return false;
}

// --------------------------- mask dtype detection ---------------------------
__global__ void k_detect(const unsigned int* mraw, int nwords, int* mode) {
    __shared__ int s_isF, s_isB;
    if (threadIdx.x == 0) { s_isF = 0; s_isB = 0; }
    __syncthreads();
    int f = 0, b = 0;
    for (int i = threadIdx.x; i < nwords; i += blockDim.x) {
        unsigned w = mraw[i];
        if (w == 0x3f800000u) f = 1;
        else if (w > 1u)      b = 1;
    }
    if (f) atomicOr(&s_isF, 1);
    if (b) atomicOr(&s_isB, 1);
    __syncthreads();
    if (threadIdx.x == 0) *mode = s_isF ? 2 : (s_isB ? 1 : 0);
}

// ------------------------------- init -------------------------------------
__global__ void k_init(const void* mraw, const int* mode_p, int N,
                       float* maskf, float* mu, float* LD, float* LDp,
                       float* LSa, float* LSb, float* LSfin, float* lsig,
                       float* err) {
    const int bb = blockIdx.x;
    const int mode = *mode_p;
    const float NEG = -__builtin_inff();

    float c = 0.f;
    for (int n = threadIdx.x; n < N; n += blockDim.x)
        c += mask_read(mraw, mode, bb * N + n) ? 1.f : 0.f;

    __shared__ float sred[256];
    sred[threadIdx.x] = c;
    __syncthreads();
    for (int o = 128; o > 0; o >>= 1) {
        if (threadIdx.x < o) sred[threadIdx.x] += sred[threadIdx.x + o];
        __syncthreads();
    }
    const float cnt = sred[0];          // >= 1 guaranteed by setup
    const float muv = 1.0f / cnt;
    const float lmu = __logf(muv);

    for (int n = threadIdx.x; n < N; n += blockDim.x) {
        int idx = bb * N + n;
        bool mv = mask_read(mraw, mode, idx);
        float z = mv ? 0.f : NEG;
        maskf[idx] = mv ? 1.f : 0.f;
        mu[idx]    = mv ? muv : 0.f;
        LD[idx]  = z;  LDp[idx] = z;
        LSa[idx] = z;  LSb[idx] = z;  LSfin[idx] = z;
        lsig[idx] = mv ? lmu : NEG;
    }
    if (bb == 0)
        for (int i = threadIdx.x; i < NITER; i += blockDim.x) err[i] = 0.f;
}

// --------------------------- b0 = (A.*T0) @ mu ------------------------------
__global__ void k_b0(const float* __restrict__ C, int bs, int N,
                     const float* LD, const float* LS, const float* lsig,
                     float* bvec) {
    const int tid  = blockIdx.x * blockDim.x + threadIdx.x;
    const int wid  = tid >> 6, lane = tid & 63;
    const int nw   = (gridDim.x * blockDim.x) >> 6;
    const int R    = bs * N;
    for (int row = wid; row < R; row += nw) {
        const int bb = row / N;
        const float ldv = LD[row];
        float acc = 0.f;
        if (ldv != -__builtin_inff()) {
            const float* crow = C + (size_t)row * N;
            const float* lsb  = LS + (size_t)bb * N;
            const float* lgb  = lsig + (size_t)bb * N;
            for (int m = lane * 4; m < N; m += 256) {
                float4 c4 = *(const float4*)(crow + m);
                float4 l4 = *(const float4*)(lsb + m);
                float4 g4 = *(const float4*)(lgb + m);
                acc += __expf(ldv + l4.x + g4.x - INVB * c4.x);
                acc += __expf(ldv + l4.y + g4.y - INVB * c4.y);
                acc += __expf(ldv + l4.z + g4.z - INVB * c4.z);
                acc += __expf(ldv + l4.w + g4.w - INVB * c4.w);
            }
        }
        acc = wave_sum(acc);
        if (lane == 0) bvec[row] = acc;
    }
}

// ---------------- col pass: delta update + partial column sums ---------------
__global__ void k_cp(const float* __restrict__ C, int R, int N, int it,
                     const float* err,
                     const float* maskf, const float* mu, const float* bvec,
                     float* LD, float* LDp, const float* LScur, float* apart) {
    if (is_done(err, it)) return;
    const int tiles = N >> 6;
    const int bb   = blockIdx.x / tiles;
    const int tile = blockIdx.x % tiles;
    const int r0   = tile << 6;
    const int t    = threadIdx.x;

    __shared__ float ld_s[64];
    if (t < 64) {
        int gr = bb * N + r0 + t;
        float mf  = maskf[gr];
        float bm  = (mf != 0.f) ? bvec[gr] : EPS;
        float dlt = mu[gr] / bm;              // 0 for invalid rows
        float ldo = LD[gr];
        float ldn = ldo + __logf(dlt);        // -inf stays -inf
        LDp[gr] = ldo;
        LD[gr]  = ldn;
        ld_s[t] = ldn;
    }
    __syncthreads();

    const float s2 = (float)(it + 1) * INVB;
    for (int m = t; m < N; m += 256) {
        const float lsv = LScur[bb * N + m];
        const float* cp = C + (size_t)(bb * N + r0) * N + m;
        float acc = 0.f;
        #pragma unroll 8
        for (int rr = 0; rr < 64; ++rr)
            acc += __expf(ld_s[rr] + lsv - s2 * cp[(size_t)rr * N]);
        apart[(size_t)tile * R + bb * N + m] = acc;   // per-tile partial, no atomics
    }
}

// ------ row pass: sigma update + err + next-iteration b (fused) --------------
__global__ void k_rp(const float* __restrict__ C, int R, int N, int it,
                     float* err,
                     const float* maskf, const float* mu, const float* LD,
                     const float* LDp, const float* LScur, float* LSnext,
                     float* LSfin, const float* apart, float* bvec) {
    if (is_done(err, it)) return;
    const int tiles = N >> 6;
    const int bb   = blockIdx.x / tiles;
    const int tile = blockIdx.x % tiles;
    const int r0   = tile << 6;
    const int t    = threadIdx.x;

    __shared__ __align__(16) float vTn[512];
    __shared__ __align__(16) float vTo[512];
    __shared__ __align__(16) float vbs[512];

    // sigma' for ALL columns (recomputed identically per block -> deterministic),
    // persisted only for this block's owned column range [r0, r0+64)
    for (int m = t; m < N; m += 256) {
        int gm = bb * N + m;
        float av = 0.f;
        for (int tl = 0; tl < tiles; ++tl) av += apart[(size_t)tl * R + gm];
        float mf  = maskf[gm];
        float am  = (mf != 0.f) ? av : EPS;
        float sg  = mu[gm] / am;               // 0 for invalid cols
        float lsg = __logf(sg);
        float lso = LScur[gm];
        float lsn = lso + lsg;
        vTo[m] = lso;
        vTn[m] = lsn;
        vbs[m] = lsn + lsg;                    // LS' + log(sigma')
        if (m >= r0 && m < r0 + 64) { LSnext[gm] = lsn; LSfin[gm] = lsn; }
    }
    __syncthreads();

    const float s1 = (float)it * INVB;
    const float s2 = (float)(it + 1) * INVB;
    const float s3 = (float)(it + 2) * INVB;
    const int lane = t & 63, wv = t >> 6;
    float errmax = 0.f;

    for (int j = 0; j < 16; ++j) {
        const int n  = r0 + wv * 16 + j;
        const int gr = bb * N + n;
        const float ldn = LD[gr], ldo = LDp[gr];
        float bacc = 0.f, eacc = 0.f;
        if (ldn != -__builtin_inff() || ldo != -__builtin_inff()) {
            const float* crow = C + (size_t)gr * N;
            for (int m = lane * 4; m < N; m += 256) {
                float4 c4  = *(const float4*)(crow + m);
                float4 tn4 = *(const float4*)(&vTn[m]);
                float4 to4 = *(const float4*)(&vTo[m]);
                float4 vb4 = *(const float4*)(&vbs[m]);
                float tn, to;
                tn = __expf(ldn + tn4.x - s2 * c4.x);
                to = __expf(ldo + to4.x - s1 * c4.x);
                eacc += fabsf(tn - to);
                bacc += __expf(ldn + vb4.x - s3 * c4.x);
                tn = __expf(ldn + tn4.y - s2 * c4.y);
                to = __expf(ldo + to4.y - s1 * c4.y);
                eacc += fabsf(tn - to);
                bacc += __expf(ldn + vb4.y - s3 * c4.y);
                tn = __expf(ldn + tn4.z - s2 * c4.z);
                to = __expf(ldo + to4.z - s1 * c4.z);
                eacc += fabsf(tn - to);
                bacc += __expf(ldn + vb4.z - s3 * c4.z);
                tn = __expf(ldn + tn4.w - s2 * c4.w);
                to = __expf(ldo + to4.w - s1 * c4.w);
                eacc += fabsf(tn - to);
                bacc += __expf(ldn + vb4.w - s3 * c4.w);
            }
        }
        bacc = wave_sum(bacc);
        eacc = wave_sum(eacc);
        if (lane == 0) { bvec[gr] = bacc; errmax = fmaxf(errmax, eacc); }
    }
    if (lane == 0)
        atomicMax((unsigned int*)err + it, __float_as_uint(errmax)); // >=0 floats: uint order == float order
}

// ---------------- final: T out, C copy, per-row T.*C sums -------------------
__global__ void k_final(const float* __restrict__ C, int bs, int N,
                        const float* LD, const float* LSfin, const float* err,
                        float* outT, float* outC, float* drow) {
    int kf = NITER;
    for (int j = 0; j < NITER; ++j)
        if (err[j] < TOL) { kf = j + 1; break; }
    const float sF = (float)kf * INVB;

    const int tid = blockIdx.x * blockDim.x + threadIdx.x;
    const int wid = tid >> 6, lane = tid & 63;
    const int nw  = (gridDim.x * blockDim.x) >> 6;
    const int R   = bs * N;
    for (int row = wid; row < R; row += nw) {
        const int bb = row / N;
        const float ldv = LD[row];
        const float* crow = C + (size_t)row * N;
        const float* lsb  = LSfin + (size_t)bb * N;
        float* trow = outT + (size_t)row * N;
        float* orow = outC + (size_t)row * N;
        float acc = 0.f;
        for (int m = lane * 4; m < N; m += 256) {
            float4 c4 = *(const float4*)(crow + m);
            float4 l4 = *(const float4*)(lsb + m);
            float4 t4;
            t4.x = __expf(ldv + l4.x - sF * c4.x);
            t4.y = __expf(ldv + l4.y - sF * c4.y);
            t4.z = __expf(ldv + l4.z - sF * c4.z);
            t4.w = __expf(ldv + l4.w - sF * c4.w);
            acc += t4.x * c4.x + t4.y * c4.y + t4.z * c4.z + t4.w * c4.w;
            *(float4*)(trow + m) = t4;
            *(float4*)(orow + m) = c4;
        }
        acc = wave_sum(acc);
        if (lane == 0) drow[row] = acc;
    }
}

// ------------------------- distance reduction -------------------------------
__global__ void k_dist(const float* drow, int N, float* outD) {
    const int bb = blockIdx.x;
    float acc = 0.f;
    for (int n = threadIdx.x; n < N; n += blockDim.x)
        acc += drow[(size_t)bb * N + n];
    __shared__ float s[256];
    s[threadIdx.x] = acc;
    __syncthreads();
    for (int o = 128; o > 0; o >>= 1) {
        if (threadIdx.x < o) s[threadIdx.x] += s[threadIdx.x + o];
        __syncthreads();
    }
    if (threadIdx.x == 0) outD[bb] = s[0];
}

// ---------------------------------------------------------------------------
extern "C" void kernel_launch(void* const* d_in, const int* in_sizes, int n_in,
                              void* d_out, int out_size, void* d_ws, size_t ws_size,
                              hipStream_t stream) {
    const float* C    = (const float*)d_in[0];
    const void*  mask = d_in[4];
    const int R  = in_sizes[4];           // bs*N
    const int N  = in_sizes[0] / R;       // 512
    const int bs = R / N;                 // 128
    const int tiles = N >> 6;             // 8

    float* wsf   = (float*)d_ws;
    float* maskf = wsf;
    float* mu    = wsf + (size_t)1 * R;
    float* LD    = wsf + (size_t)2 * R;
    float* LDp   = wsf + (size_t)3 * R;
    float* LSa   = wsf + (size_t)4 * R;
    float* LSb   = wsf + (size_t)5 * R;
    float* LSfin = wsf + (size_t)6 * R;
    float* lsig  = wsf + (size_t)7 * R;
    float* bvec  = wsf + (size_t)8 * R;
    float* drow  = wsf + (size_t)9 * R;
    float* apart = wsf + (size_t)10 * R;            // tiles * R
    float* err   = wsf + (size_t)(10 + tiles) * R;  // NITER floats
    int*   mode  = (int*)(err + NITER);

    float* outD = (float*)d_out;
    float* outT = outD + bs;
    float* outC = outT + (size_t)bs * N * N;

    k_detect<<<1, 256, 0, stream>>>((const unsigned int*)mask, R / 4, mode);
    k_init<<<bs, 256, 0, stream>>>(mask, mode, N, maskf, mu, LD, LDp,
                                   LSa, LSb, LSfin, lsig, err);
    k_b0<<<1024, 256, 0, stream>>>(C, bs, N, LD, LSa, lsig, bvec);

    for (int it = 0; it < NITER; ++it) {
        const float* LScur = (it & 1) ? LSb : LSa;
        float*       LSnxt = (it & 1) ? LSa : LSb;
        k_cp<<<bs * tiles, 256, 0, stream>>>(C, R, N, it, err, maskf, mu, bvec,
                                             LD, LDp, LScur, apart);
        k_rp<<<bs * tiles, 256, 0, stream>>>(C, R, N, it, err, maskf, mu, LD,
                                             LDp, LScur, LSnxt, LSfin, apart, bvec);
    }

    k_final<<<1024, 256, 0, stream>>>(C, bs, N, LD, LSfin, err, outT, outC, drow);
    k_dist<<<bs, 256, 0, stream>>>(drow, N, outD);
}